// Round 4
// baseline (336.899 us; speedup 1.0000x reference)
//
#include <hip/hip_runtime.h>

#define NCV 100000
#define NTV 300000
#define NPV 50000
#define OUTC 10
#define EMV 300000
#define EIV 600000
#define YST 16   // y_c / y_p row stride (floats) -> 64B-aligned rows

// slot-row capacities (Poisson tails on fixed dataset; overflow prob ~1e-8, clamped)
#define KC 32    // transactions per customer  (mean 3)
#define KP 64    // transactions per product   (mean 12)
#define KTM 16   // customers per transaction  (mean 1)
#define KTI 20   // products per transaction   (mean 2)

// ---------------- K0: per-column weight folding (blocks 0..9) + cnt zero (blocks 10+) ----
// Column o of: T1=Wn10@Wout, T2=Wn12@Wout, T3=0.5*(Wr10+Wr12)@Wout (128 each, LDS)
//             Q1=Wn01@T1 Q2=Wr01@T1 Q3=Wn03@T2 Q4=Wr03@T2 Q5=Wn00@T3 Q6=Wn02@T3 Q7=(Wr00+Wr02)@T3
//             B[:,o]: 45 entries (0..16 B_c | 17..33 B_p | 34..41 B_t | 42 u_c | 43 u_p | 44 k)
__global__ __launch_bounds__(256) void fold_init(
    const float* __restrict__ Wcol, const float* __restrict__ bcol,
    const float* __restrict__ Wn, const float* __restrict__ Wr,
    const float* __restrict__ b_lin, const float* __restrict__ Wout,
    const float* __restrict__ bout,
    int* __restrict__ cnts, int ncnt4, float* __restrict__ B) {
  int tid = threadIdx.x;
  if (blockIdx.x >= 10) {   // zero the cnt block (int4 grid-stride)
    int i = (blockIdx.x - 10) * 256 + tid;
    int stride = (gridDim.x - 10) * 256;
    int4 z = make_int4(0, 0, 0, 0);
    for (; i < ncnt4; i += stride) ((int4*)cnts)[i] = z;
    return;
  }
  __shared__ float sWo[128];
  __shared__ float sT[3][128];
  __shared__ float sQ[7][128];
  const int o = blockIdx.x;
  if (tid < 128) sWo[tid] = Wout[tid * 10 + o];
  __syncthreads();

  const float* Wn00 = Wn;               const float* Wn01 = Wn + 16384;
  const float* Wn02 = Wn + 2 * 16384;   const float* Wn03 = Wn + 3 * 16384;
  const float* Wn10 = Wn + 4 * 16384;   const float* Wn12 = Wn + 6 * 16384;
  const float* Wr00 = Wr;               const float* Wr01 = Wr + 16384;
  const float* Wr02 = Wr + 2 * 16384;   const float* Wr03 = Wr + 3 * 16384;
  const float* Wr10 = Wr + 4 * 16384;   const float* Wr12 = Wr + 6 * 16384;

  // ---- T phase: 3 mats x 128 rows, one dot(128) per task ----
  for (int task = tid; task < 384; task += 256) {
    int mat = task >> 7, n = task & 127;
    float acc = 0.f;
    if (mat == 0) {
      const float4* w = (const float4*)(Wn10 + n * 128);
      for (int m = 0; m < 32; ++m) {
        float4 w4 = w[m];
        acc += w4.x * sWo[4 * m] + w4.y * sWo[4 * m + 1] +
               w4.z * sWo[4 * m + 2] + w4.w * sWo[4 * m + 3];
      }
    } else if (mat == 1) {
      const float4* w = (const float4*)(Wn12 + n * 128);
      for (int m = 0; m < 32; ++m) {
        float4 w4 = w[m];
        acc += w4.x * sWo[4 * m] + w4.y * sWo[4 * m + 1] +
               w4.z * sWo[4 * m + 2] + w4.w * sWo[4 * m + 3];
      }
    } else {
      const float4* wa = (const float4*)(Wr10 + n * 128);
      const float4* wb = (const float4*)(Wr12 + n * 128);
      for (int m = 0; m < 32; ++m) {
        float4 a = wa[m], b = wb[m];
        acc += 0.5f * ((a.x + b.x) * sWo[4 * m] + (a.y + b.y) * sWo[4 * m + 1] +
                       (a.z + b.z) * sWo[4 * m + 2] + (a.w + b.w) * sWo[4 * m + 3]);
      }
    }
    sT[mat][n] = acc;
  }
  __syncthreads();

  // ---- Q phase: 7 mats x 128 rows ----
  for (int task = tid; task < 896; task += 256) {
    int q = task / 128, k = task & 127;
    const float* Tc = sT[q < 2 ? 0 : (q < 4 ? 1 : 2)];
    const float4* w; const float4* w2 = nullptr;
    switch (q) {
      case 0: w = (const float4*)(Wn01 + k * 128); break;
      case 1: w = (const float4*)(Wr01 + k * 128); break;
      case 2: w = (const float4*)(Wn03 + k * 128); break;
      case 3: w = (const float4*)(Wr03 + k * 128); break;
      case 4: w = (const float4*)(Wn00 + k * 128); break;
      case 5: w = (const float4*)(Wn02 + k * 128); break;
      default: w = (const float4*)(Wr00 + k * 128); w2 = (const float4*)(Wr02 + k * 128); break;
    }
    float acc = 0.f;
    for (int n = 0; n < 32; ++n) {
      float4 w4 = w[n];
      if (w2) { float4 b = w2[n]; w4.x += b.x; w4.y += b.y; w4.z += b.z; w4.w += b.w; }
      acc += w4.x * Tc[4 * n] + w4.y * Tc[4 * n + 1] +
             w4.z * Tc[4 * n + 2] + w4.w * Tc[4 * n + 3];
    }
    sQ[q][k] = acc;
  }
  __syncthreads();

  // ---- B phase: 45 rows of column o ----
  if (tid < 45) {
    int r = tid;
    const float* WcC = Wcol, *WcT = Wcol + 128, *WcP = Wcol + 256;
    const float* bC = bcol, *bT = bcol + 128, *bP = bcol + 256;
    const float* b00 = b_lin, *b01 = b_lin + 128, *b02 = b_lin + 256, *b03 = b_lin + 384;
    const float* b10 = b_lin + 512, *b12 = b_lin + 768;
    float s = 0.f;
    if (r < 8) {
      for (int j = 0; j < 16; ++j) s += WcT[r * 16 + j] * sQ[0][r * 16 + j];
    } else if (r < 16) {
      int jr = r - 8;
      for (int j = 0; j < 16; ++j)
        s += WcC[jr * 16 + j] * (sQ[1][jr * 16 + j] + sQ[4][jr * 16 + j]);
    } else if (r == 16) {
      for (int k = 0; k < 128; ++k) s += bT[k] * sQ[0][k];
    } else if (r < 25) {
      int jr = r - 17;
      for (int j = 0; j < 16; ++j) s += WcT[jr * 16 + j] * sQ[2][jr * 16 + j];
    } else if (r < 33) {
      int jr = r - 25;
      for (int j = 0; j < 16; ++j)
        s += WcP[jr * 16 + j] * (sQ[3][jr * 16 + j] + sQ[5][jr * 16 + j]);
    } else if (r == 33) {
      for (int k = 0; k < 128; ++k) s += bT[k] * sQ[2][k];
    } else if (r < 42) {
      int jr = r - 34;
      for (int j = 0; j < 16; ++j) s += WcT[jr * 16 + j] * sQ[6][jr * 16 + j];
    } else if (r == 42) {
      for (int k = 0; k < 128; ++k)
        s += bC[k] * (sQ[1][k] + sQ[4][k]) + b01[k] * sT[0][k];
    } else if (r == 43) {
      for (int k = 0; k < 128; ++k)
        s += bP[k] * (sQ[3][k] + sQ[5][k]) + b03[k] * sT[1][k];
    } else {
      for (int n = 0; n < 128; ++n)
        s += (b10[n] + b12[n]) * sWo[n] + bT[n] * sQ[6][n] + (b00[n] + b02[n]) * sT[2][n];
    }
    float v = s * 0.5f;
    if (r == 44) v += bout[o];
    B[r * 10 + o] = v;
  }
}

// ---------------- K1: build fixed-capacity slot arrays (bucketed CSR) -------------
// slot = atomicAdd(&cnt[node],1); slots[node*K + slot] = other endpoint.
// Same returning-atomic count as linked lists, but gathers become contiguous scans.
__global__ __launch_bounds__(256) void build_slots(
    const int* __restrict__ ems, const int* __restrict__ emd,
    const int* __restrict__ eis, const int* __restrict__ eid,
    int* __restrict__ cnt_c, int* __restrict__ cnt_p,
    int* __restrict__ cnt_tm, int* __restrict__ cnt_ti,
    int* __restrict__ slot_c, int* __restrict__ slot_p,
    int* __restrict__ slot_tm, int* __restrict__ slot_ti) {
  int e = blockIdx.x * 256 + threadIdx.x;
  if (e < EMV) {
    int c = ems[e], t = emd[e];
    int sc = atomicAdd(&cnt_c[c], 1);
    if (sc < KC) slot_c[(size_t)c * KC + sc] = t;
    int st = atomicAdd(&cnt_tm[t], 1);
    if (st < KTM) slot_tm[(size_t)t * KTM + st] = c;
  }
  if (e < EIV) {
    int p = eis[e], t = eid[e];
    int sp = atomicAdd(&cnt_p[p], 1);
    if (sp < KP) slot_p[(size_t)p * KP + sp] = t;
    int st = atomicAdd(&cnt_ti[t], 1);
    if (st < KTI) slot_ti[(size_t)t * KTI + st] = p;
  }
}

// ---------------- K2: gather x_t over slot rows + project y -------------------------
// Per node: n = cnt, slots row contiguous; 4-wide int4 slot loads -> 8 independent
// float4 x_t loads in flight. z = [g*mean_xt, x_own, g] @ B -> 10 floats.
__global__ __launch_bounds__(256) void gather_y(
    const float* __restrict__ xt,
    const int* __restrict__ cnt_c, const int* __restrict__ cnt_p,
    const int* __restrict__ slot_c, const int* __restrict__ slot_p,
    const float* __restrict__ xc, const float* __restrict__ xp,
    const float* __restrict__ B,
    float* __restrict__ y_c, float* __restrict__ y_p) {
  __shared__ float sB[340];   // rows 0..33 of B
  int tid = threadIdx.x;
  for (int i = tid; i < 340; i += 256) sB[i] = B[i];
  __syncthreads();
  int i = blockIdx.x * 256 + tid;
  if (i >= NCV + NPV) return;
  bool isC = i < NCV;
  int idx = isC ? i : i - NCV;
  int cnt = isC ? cnt_c[idx] : cnt_p[idx];
  int n = min(cnt, isC ? KC : KP);
  const int* slots = isC ? (slot_c + (size_t)idx * KC) : (slot_p + (size_t)idx * KP);

  float acc[8] = {0.f, 0.f, 0.f, 0.f, 0.f, 0.f, 0.f, 0.f};
  for (int base = 0; base < n; base += 4) {
    int4 s4 = *(const int4*)(slots + base);
    int m = n - base;
    // clamp indices for safety; guard accumulation (keeps all loads unconditional -> MLP)
    int i0 = s4.x;
    int i1 = m > 1 ? s4.y : s4.x;
    int i2 = m > 2 ? s4.z : s4.x;
    int i3 = m > 3 ? s4.w : s4.x;
    const float4* r0 = (const float4*)(xt + (size_t)i0 * 8);
    const float4* r1 = (const float4*)(xt + (size_t)i1 * 8);
    const float4* r2 = (const float4*)(xt + (size_t)i2 * 8);
    const float4* r3 = (const float4*)(xt + (size_t)i3 * 8);
    float4 a0 = r0[0], b0 = r0[1];
    float4 a1 = r1[0], b1 = r1[1];
    float4 a2 = r2[0], b2 = r2[1];
    float4 a3 = r3[0], b3 = r3[1];
    acc[0] += a0.x; acc[1] += a0.y; acc[2] += a0.z; acc[3] += a0.w;
    acc[4] += b0.x; acc[5] += b0.y; acc[6] += b0.z; acc[7] += b0.w;
    if (m > 1) {
      acc[0] += a1.x; acc[1] += a1.y; acc[2] += a1.z; acc[3] += a1.w;
      acc[4] += b1.x; acc[5] += b1.y; acc[6] += b1.z; acc[7] += b1.w;
    }
    if (m > 2) {
      acc[0] += a2.x; acc[1] += a2.y; acc[2] += a2.z; acc[3] += a2.w;
      acc[4] += b2.x; acc[5] += b2.y; acc[6] += b2.z; acc[7] += b2.w;
    }
    if (m > 3) {
      acc[0] += a3.x; acc[1] += a3.y; acc[2] += a3.z; acc[3] += a3.w;
      acc[4] += b3.x; acc[5] += b3.y; acc[6] += b3.z; acc[7] += b3.w;
    }
  }

  const float* xo = (isC ? xc : xp) + (size_t)idx * 8;
  const float* Bs = sB + (isC ? 0 : 170);
  float cntf = (float)cnt;
  float gg = cnt > 0 ? 1.f : 0.f;
  float inv = gg / fmaxf(cntf, 1.f);
  float lg[OUTC];
  #pragma unroll
  for (int o = 0; o < OUTC; ++o) lg[o] = gg * Bs[16 * 10 + o];
  #pragma unroll
  for (int r = 0; r < 8; ++r) {
    float zb = acc[r] * inv;
    float zo = xo[r];
    #pragma unroll
    for (int o = 0; o < OUTC; ++o)
      lg[o] += zb * Bs[r * 10 + o] + zo * Bs[(8 + r) * 10 + o];
  }
  float* y = (isC ? y_c : y_p) + (size_t)idx * YST;
  #pragma unroll
  for (int o = 0; o < OUTC; ++o) y[o] = lg[o];
}

// ---------------- K3: gather y over slot rows + combine + softmax --------------------
__global__ __launch_bounds__(256) void gather_t(
    const float* __restrict__ y_c, const float* __restrict__ y_p,
    const float* __restrict__ xt,
    const int* __restrict__ cnt_tm, const int* __restrict__ cnt_ti,
    const int* __restrict__ slot_tm, const int* __restrict__ slot_ti,
    const float* __restrict__ B, float* __restrict__ out) {
  __shared__ float sB[110];   // rows 34..44 of B
  int tid = threadIdx.x;
  for (int i = tid; i < 110; i += 256) sB[i] = B[340 + i];
  __syncthreads();
  int t = blockIdx.x * 256 + tid;
  if (t >= NTV) return;

  int dcc = cnt_tm[t], dpp = cnt_ti[t];
  int nc = min(dcc, KTM), np = min(dpp, KTI);
  const int* scs = slot_tm + (size_t)t * KTM;
  const int* sps = slot_ti + (size_t)t * KTI;

  float sc[OUTC] = {0.f, 0.f, 0.f, 0.f, 0.f, 0.f, 0.f, 0.f, 0.f, 0.f};
  float sp[OUTC] = {0.f, 0.f, 0.f, 0.f, 0.f, 0.f, 0.f, 0.f, 0.f, 0.f};
  for (int base = 0; base < nc; base += 2) {
    int j0 = scs[base];
    int j1 = (nc - base > 1) ? scs[base + 1] : j0;
    const float* y0 = y_c + (size_t)j0 * YST;
    const float* y1 = y_c + (size_t)j1 * YST;
    float4 u0 = *(const float4*)y0, w0 = *(const float4*)(y0 + 4);
    float2 z0 = *(const float2*)(y0 + 8);
    float4 u1 = *(const float4*)y1, w1 = *(const float4*)(y1 + 4);
    float2 z1 = *(const float2*)(y1 + 8);
    sc[0] += u0.x; sc[1] += u0.y; sc[2] += u0.z; sc[3] += u0.w;
    sc[4] += w0.x; sc[5] += w0.y; sc[6] += w0.z; sc[7] += w0.w;
    sc[8] += z0.x; sc[9] += z0.y;
    if (nc - base > 1) {
      sc[0] += u1.x; sc[1] += u1.y; sc[2] += u1.z; sc[3] += u1.w;
      sc[4] += w1.x; sc[5] += w1.y; sc[6] += w1.z; sc[7] += w1.w;
      sc[8] += z1.x; sc[9] += z1.y;
    }
  }
  for (int base = 0; base < np; base += 2) {
    int j0 = sps[base];
    int j1 = (np - base > 1) ? sps[base + 1] : j0;
    const float* y0 = y_p + (size_t)j0 * YST;
    const float* y1 = y_p + (size_t)j1 * YST;
    float4 u0 = *(const float4*)y0, w0 = *(const float4*)(y0 + 4);
    float2 z0 = *(const float2*)(y0 + 8);
    float4 u1 = *(const float4*)y1, w1 = *(const float4*)(y1 + 4);
    float2 z1 = *(const float2*)(y1 + 8);
    sp[0] += u0.x; sp[1] += u0.y; sp[2] += u0.z; sp[3] += u0.w;
    sp[4] += w0.x; sp[5] += w0.y; sp[6] += w0.z; sp[7] += w0.w;
    sp[8] += z0.x; sp[9] += z0.y;
    if (np - base > 1) {
      sp[0] += u1.x; sp[1] += u1.y; sp[2] += u1.z; sp[3] += u1.w;
      sp[4] += w1.x; sp[5] += w1.y; sp[6] += w1.z; sp[7] += w1.w;
      sp[8] += z1.x; sp[9] += z1.y;
    }
  }

  float Gc = dcc > 0 ? 1.f : 0.f, Gp = dpp > 0 ? 1.f : 0.f;
  float ivc = 1.f / fmaxf((float)dcc, 1.f), ivp = 1.f / fmaxf((float)dpp, 1.f);

  const float4* xp4 = (const float4*)(xt + (size_t)t * 8);
  float4 xa = xp4[0], xb = xp4[1];
  float xv[8] = {xa.x, xa.y, xa.z, xa.w, xb.x, xb.y, xb.z, xb.w};

  float lg[OUTC];
  #pragma unroll
  for (int o = 0; o < OUTC; ++o)
    lg[o] = sc[o] * ivc + sp[o] * ivp +
            Gc * sB[80 + o] + Gp * sB[90 + o] + sB[100 + o];
  #pragma unroll
  for (int r = 0; r < 8; ++r) {
    float xr = xv[r];
    #pragma unroll
    for (int o = 0; o < OUTC; ++o) lg[o] += xr * sB[r * 10 + o];
  }

  float m = lg[0];
  #pragma unroll
  for (int o = 1; o < OUTC; ++o) m = fmaxf(m, lg[o]);
  float s = 0.f;
  #pragma unroll
  for (int o = 0; o < OUTC; ++o) { lg[o] = __expf(lg[o] - m); s += lg[o]; }
  float invs = 1.0f / s;
  float* op = &out[(size_t)t * OUTC];
  #pragma unroll
  for (int o = 0; o < 5; ++o) {
    float2 p2; p2.x = lg[2 * o] * invs; p2.y = lg[2 * o + 1] * invs;
    *(float2*)&op[2 * o] = p2;
  }
}

extern "C" void kernel_launch(void* const* d_in, const int* in_sizes, int n_in,
                              void* d_out, int out_size, void* d_ws, size_t ws_size,
                              hipStream_t stream) {
  const float* x_c   = (const float*)d_in[0];
  const float* x_t   = (const float*)d_in[1];
  const float* x_p   = (const float*)d_in[2];
  const float* W_col = (const float*)d_in[3];
  const float* b_col = (const float*)d_in[4];
  const float* Wn    = (const float*)d_in[5];
  const float* Wr    = (const float*)d_in[6];
  const float* b_lin = (const float*)d_in[7];
  const float* W_out = (const float*)d_in[8];
  const float* b_out = (const float*)d_in[9];
  const int* e_m_src = (const int*)d_in[10];
  const int* e_m_dst = (const int*)d_in[11];
  const int* e_i_src = (const int*)d_in[12];
  const int* e_i_dst = (const int*)d_in[13];
  float* out = (float*)d_out;

  // ---- workspace carve-out (~82 MB; ws_size = 256 MiB) ----
  size_t cursor = 0;
  char* base = (char*)d_ws;
  auto alloc = [&](size_t bytes) {
    void* p = base + cursor;
    cursor += (bytes + 255) & ~(size_t)255;
    return p;
  };
  float* y_c  = (float*)alloc((size_t)NCV * YST * 4);              // 6.4 MB
  float* y_p  = (float*)alloc((size_t)NPV * YST * 4);              // 3.2 MB
  int ncnt = NCV + NPV + 2 * NTV;                                  // 750K (mult of 4)
  int* cnts   = (int*)alloc((size_t)ncnt * 4);                     // 3.0 MB
  int* cnt_c  = cnts;
  int* cnt_p  = cnts + NCV;
  int* cnt_tm = cnts + NCV + NPV;
  int* cnt_ti = cnts + NCV + NPV + NTV;
  int* slot_c  = (int*)alloc((size_t)NCV * KC * 4);                // 12.8 MB
  int* slot_p  = (int*)alloc((size_t)NPV * KP * 4);                // 12.8 MB
  int* slot_tm = (int*)alloc((size_t)NTV * KTM * 4);               // 19.2 MB
  int* slot_ti = (int*)alloc((size_t)NTV * KTI * 4);               // 24.0 MB
  float* B    = (float*)alloc(450 * 4);

  // ---- K0: fused per-column folding (blocks 0..9) + cnt zeroing (blocks 10..127) ----
  fold_init<<<128, 256, 0, stream>>>(
      W_col, b_col, Wn, Wr, b_lin, W_out, b_out, cnts, ncnt / 4, B);

  // ---- K1: build slot arrays ----
  build_slots<<<(EIV + 255) / 256, 256, 0, stream>>>(
      e_m_src, e_m_dst, e_i_src, e_i_dst,
      cnt_c, cnt_p, cnt_tm, cnt_ti,
      slot_c, slot_p, slot_tm, slot_ti);

  // ---- K2: gather x_t over slot rows + project y ----
  gather_y<<<(NCV + NPV + 255) / 256, 256, 0, stream>>>(
      x_t, cnt_c, cnt_p, slot_c, slot_p, x_c, x_p, B, y_c, y_p);

  // ---- K3: gather y over slot rows + combine + softmax ----
  gather_t<<<(NTV + 255) / 256, 256, 0, stream>>>(
      y_c, y_p, x_t, cnt_tm, cnt_ti, slot_tm, slot_ti, B, out);
}

// Round 5
// 294.613 us; speedup vs baseline: 1.1435x; 1.1435x over previous
//
#include <hip/hip_runtime.h>

#define NCV 100000
#define NTV 300000
#define NPV 50000
#define OUTC 10
#define EMV 300000
#define EIV 600000

__device__ __forceinline__ float i2f(int v) { return __int_as_float(v); }
__device__ __forceinline__ int f2i(float v) { return __float_as_int(v); }

// ---------------- K0: per-column weight folding (blocks 0..9) + heads init (blocks 10+) ----
// Column o of: T1=Wn10@Wout, T2=Wn12@Wout, T3=0.5*(Wr10+Wr12)@Wout (128 each, LDS)
//             Q1=Wn01@T1 Q2=Wr01@T1 Q3=Wn03@T2 Q4=Wr03@T2 Q5=Wn00@T3 Q6=Wn02@T3 Q7=(Wr00+Wr02)@T3
//             B[:,o]: 45 entries (0..16 B_c | 17..33 B_p | 34..41 B_t | 42 u_c | 43 u_p | 44 k)
__global__ __launch_bounds__(256) void fold_heads(
    const float* __restrict__ Wcol, const float* __restrict__ bcol,
    const float* __restrict__ Wn, const float* __restrict__ Wr,
    const float* __restrict__ b_lin, const float* __restrict__ Wout,
    const float* __restrict__ bout,
    int* __restrict__ heads, int nheads, float* __restrict__ B) {
  int tid = threadIdx.x;
  if (blockIdx.x >= 10) {   // heads init to -1
    int i = (blockIdx.x - 10) * 256 + tid;
    int stride = (gridDim.x - 10) * 256;
    for (; i < nheads; i += stride) heads[i] = -1;
    return;
  }
  __shared__ float sWo[128];
  __shared__ float sT[3][128];
  __shared__ float sQ[7][128];
  const int o = blockIdx.x;
  if (tid < 128) sWo[tid] = Wout[tid * 10 + o];
  __syncthreads();

  const float* Wn00 = Wn;               const float* Wn01 = Wn + 16384;
  const float* Wn02 = Wn + 2 * 16384;   const float* Wn03 = Wn + 3 * 16384;
  const float* Wn10 = Wn + 4 * 16384;   const float* Wn12 = Wn + 6 * 16384;
  const float* Wr00 = Wr;               const float* Wr01 = Wr + 16384;
  const float* Wr02 = Wr + 2 * 16384;   const float* Wr03 = Wr + 3 * 16384;
  const float* Wr10 = Wr + 4 * 16384;   const float* Wr12 = Wr + 6 * 16384;

  // ---- T phase: 3 mats x 128 rows, one dot(128) per task ----
  for (int task = tid; task < 384; task += 256) {
    int mat = task >> 7, n = task & 127;
    float acc = 0.f;
    if (mat == 0) {
      const float4* w = (const float4*)(Wn10 + n * 128);
      for (int m = 0; m < 32; ++m) {
        float4 w4 = w[m];
        acc += w4.x * sWo[4 * m] + w4.y * sWo[4 * m + 1] +
               w4.z * sWo[4 * m + 2] + w4.w * sWo[4 * m + 3];
      }
    } else if (mat == 1) {
      const float4* w = (const float4*)(Wn12 + n * 128);
      for (int m = 0; m < 32; ++m) {
        float4 w4 = w[m];
        acc += w4.x * sWo[4 * m] + w4.y * sWo[4 * m + 1] +
               w4.z * sWo[4 * m + 2] + w4.w * sWo[4 * m + 3];
      }
    } else {
      const float4* wa = (const float4*)(Wr10 + n * 128);
      const float4* wb = (const float4*)(Wr12 + n * 128);
      for (int m = 0; m < 32; ++m) {
        float4 a = wa[m], b = wb[m];
        acc += 0.5f * ((a.x + b.x) * sWo[4 * m] + (a.y + b.y) * sWo[4 * m + 1] +
                       (a.z + b.z) * sWo[4 * m + 2] + (a.w + b.w) * sWo[4 * m + 3]);
      }
    }
    sT[mat][n] = acc;
  }
  __syncthreads();

  // ---- Q phase: 7 mats x 128 rows ----
  for (int task = tid; task < 896; task += 256) {
    int q = task / 128, k = task & 127;
    const float* Tc = sT[q < 2 ? 0 : (q < 4 ? 1 : 2)];
    const float4* w; const float4* w2 = nullptr;
    switch (q) {
      case 0: w = (const float4*)(Wn01 + k * 128); break;
      case 1: w = (const float4*)(Wr01 + k * 128); break;
      case 2: w = (const float4*)(Wn03 + k * 128); break;
      case 3: w = (const float4*)(Wr03 + k * 128); break;
      case 4: w = (const float4*)(Wn00 + k * 128); break;
      case 5: w = (const float4*)(Wn02 + k * 128); break;
      default: w = (const float4*)(Wr00 + k * 128); w2 = (const float4*)(Wr02 + k * 128); break;
    }
    float acc = 0.f;
    for (int n = 0; n < 32; ++n) {
      float4 w4 = w[n];
      if (w2) { float4 b = w2[n]; w4.x += b.x; w4.y += b.y; w4.z += b.z; w4.w += b.w; }
      acc += w4.x * Tc[4 * n] + w4.y * Tc[4 * n + 1] +
             w4.z * Tc[4 * n + 2] + w4.w * Tc[4 * n + 3];
    }
    sQ[q][k] = acc;
  }
  __syncthreads();

  // ---- B phase: 45 rows of column o ----
  if (tid < 45) {
    int r = tid;
    const float* WcC = Wcol, *WcT = Wcol + 128, *WcP = Wcol + 256;
    const float* bC = bcol, *bT = bcol + 128, *bP = bcol + 256;
    const float* b00 = b_lin, *b01 = b_lin + 128, *b02 = b_lin + 256, *b03 = b_lin + 384;
    const float* b10 = b_lin + 512, *b12 = b_lin + 768;
    float s = 0.f;
    if (r < 8) {
      for (int j = 0; j < 16; ++j) s += WcT[r * 16 + j] * sQ[0][r * 16 + j];
    } else if (r < 16) {
      int jr = r - 8;
      for (int j = 0; j < 16; ++j)
        s += WcC[jr * 16 + j] * (sQ[1][jr * 16 + j] + sQ[4][jr * 16 + j]);
    } else if (r == 16) {
      for (int k = 0; k < 128; ++k) s += bT[k] * sQ[0][k];
    } else if (r < 25) {
      int jr = r - 17;
      for (int j = 0; j < 16; ++j) s += WcT[jr * 16 + j] * sQ[2][jr * 16 + j];
    } else if (r < 33) {
      int jr = r - 25;
      for (int j = 0; j < 16; ++j)
        s += WcP[jr * 16 + j] * (sQ[3][jr * 16 + j] + sQ[5][jr * 16 + j]);
    } else if (r == 33) {
      for (int k = 0; k < 128; ++k) s += bT[k] * sQ[2][k];
    } else if (r < 42) {
      int jr = r - 34;
      for (int j = 0; j < 16; ++j) s += WcT[jr * 16 + j] * sQ[6][jr * 16 + j];
    } else if (r == 42) {
      for (int k = 0; k < 128; ++k)
        s += bC[k] * (sQ[1][k] + sQ[4][k]) + b01[k] * sT[0][k];
    } else if (r == 43) {
      for (int k = 0; k < 128; ++k)
        s += bP[k] * (sQ[3][k] + sQ[5][k]) + b03[k] * sT[1][k];
    } else {
      for (int n = 0; n < 128; ++n)
        s += (b10[n] + b12[n]) * sWo[n] + bT[n] * sQ[6][n] + (b00[n] + b02[n]) * sT[2][n];
    }
    float v = s * 0.5f;
    if (r == 44) v += bout[o];
    B[r * 10 + o] = v;
  }
}

// ---------------- K1: build lists with FAT c/p-nodes ---------------------------------
// cnode[e] (64B, 4x int4, written coalesced at own index e):
//   word0 = {c_next, t_next, x_t[0], x_t[1]}   word1 = {x_t[2..5]}
//   word2 = {x_t[6], x_t[7], 0, 0}             word3 = {0,0,0,0}
// Both exch results land in the node so gather_y can later fill the t-side node.
__global__ __launch_bounds__(256) void build_graph(
    const int* __restrict__ ems, const int* __restrict__ emd,
    const int* __restrict__ eis, const int* __restrict__ eid,
    const float* __restrict__ xt,
    int* __restrict__ head_c, int* __restrict__ head_p,
    int* __restrict__ head_tm, int* __restrict__ head_ti,
    int4* __restrict__ cnm, int4* __restrict__ cni) {
  int e = blockIdx.x * 256 + threadIdx.x;
  int4 z = make_int4(0, 0, 0, 0);
  if (e < EMV) {
    int c = ems[e], t = emd[e];
    int cn = atomicExch(&head_c[c], e);
    int tn = atomicExch(&head_tm[t], e);
    const int4* xr = (const int4*)(xt + (size_t)t * 8);
    int4 x0 = xr[0], x1 = xr[1];
    cnm[4 * (size_t)e]     = make_int4(cn, tn, x0.x, x0.y);
    cnm[4 * (size_t)e + 1] = make_int4(x0.z, x0.w, x1.x, x1.y);
    cnm[4 * (size_t)e + 2] = make_int4(x1.z, x1.w, 0, 0);
    cnm[4 * (size_t)e + 3] = z;
  }
  if (e < EIV) {
    int p = eis[e], t = eid[e];
    int pn = atomicExch(&head_p[p], e);
    int tn = atomicExch(&head_ti[t], e);
    const int4* xr = (const int4*)(xt + (size_t)t * 8);
    int4 x0 = xr[0], x1 = xr[1];
    cni[4 * (size_t)e]     = make_int4(pn, tn, x0.x, x0.y);
    cni[4 * (size_t)e + 1] = make_int4(x0.z, x0.w, x1.x, x1.y);
    cni[4 * (size_t)e + 2] = make_int4(x1.z, x1.w, 0, 0);
    cni[4 * (size_t)e + 3] = z;
  }
}

// ---------------- K2: walk c/p lists (1 line/edge), project y, write FAT t-nodes -----
// tnode[e] (64B, full-line write, no races - each edge has exactly one c/p owner):
//   word0 = {t_next, y0, y1, y2}  word1 = {y3..y6}  word2 = {y7, y8, y9, 0}  word3 = 0
__global__ __launch_bounds__(256) void gather_y(
    const int* __restrict__ head_c, const int* __restrict__ head_p,
    const int4* __restrict__ cnm, const int4* __restrict__ cni,
    const float* __restrict__ xc, const float* __restrict__ xp,
    const float* __restrict__ B,
    int4* __restrict__ tnm, int4* __restrict__ tni) {
  __shared__ float sB[340];   // rows 0..33 of B
  int tid = threadIdx.x;
  for (int i = tid; i < 340; i += 256) sB[i] = B[i];
  __syncthreads();
  int i = blockIdx.x * 256 + tid;
  if (i >= NCV + NPV) return;
  bool isC = i < NCV;
  int idx = isC ? i : i - NCV;
  const int4* cn = isC ? cnm : cni;
  int4* tn = isC ? tnm : tni;
  int head = isC ? head_c[idx] : head_p[idx];

  float acc[8] = {0.f, 0.f, 0.f, 0.f, 0.f, 0.f, 0.f, 0.f};
  float cnt = 0.f;
  int e = head;
  while (e >= 0) {
    int4 w0 = cn[4 * (size_t)e];
    int4 w1 = cn[4 * (size_t)e + 1];
    int4 w2 = cn[4 * (size_t)e + 2];
    acc[0] += i2f(w0.z); acc[1] += i2f(w0.w);
    acc[2] += i2f(w1.x); acc[3] += i2f(w1.y);
    acc[4] += i2f(w1.z); acc[5] += i2f(w1.w);
    acc[6] += i2f(w2.x); acc[7] += i2f(w2.y);
    cnt += 1.f;
    e = w0.x;
  }

  const float* xo = (isC ? xc : xp) + (size_t)idx * 8;
  const float* Bs = sB + (isC ? 0 : 170);
  float gg = cnt > 0.f ? 1.f : 0.f;
  float inv = gg / fmaxf(cnt, 1.f);
  float lg[OUTC];
  #pragma unroll
  for (int o = 0; o < OUTC; ++o) lg[o] = gg * Bs[16 * 10 + o];
  #pragma unroll
  for (int r = 0; r < 8; ++r) {
    float zb = acc[r] * inv;
    float zo = xo[r];
    #pragma unroll
    for (int o = 0; o < OUTC; ++o)
      lg[o] += zb * Bs[r * 10 + o] + zo * Bs[(8 + r) * 10 + o];
  }

  // second walk (nodes L1-hot): write fat t-side nodes, full 64B lines
  int4 y1 = make_int4(f2i(lg[3]), f2i(lg[4]), f2i(lg[5]), f2i(lg[6]));
  int4 y2 = make_int4(f2i(lg[7]), f2i(lg[8]), f2i(lg[9]), 0);
  int4 z = make_int4(0, 0, 0, 0);
  e = head;
  while (e >= 0) {
    int4 w0 = cn[4 * (size_t)e];
    tn[4 * (size_t)e]     = make_int4(w0.y, f2i(lg[0]), f2i(lg[1]), f2i(lg[2]));
    tn[4 * (size_t)e + 1] = y1;
    tn[4 * (size_t)e + 2] = y2;
    tn[4 * (size_t)e + 3] = z;
    e = w0.x;
  }
}

// ---------------- K3: walk t-lists (1 line/edge, dual interleaved) + combine + softmax
__global__ __launch_bounds__(256) void gather_t(
    const int4* __restrict__ tnm, const int4* __restrict__ tni,
    const float* __restrict__ xt,
    const int* __restrict__ head_tm, const int* __restrict__ head_ti,
    const float* __restrict__ B, float* __restrict__ out) {
  __shared__ float sB[110];   // rows 34..44 of B
  int tid = threadIdx.x;
  for (int i = tid; i < 110; i += 256) sB[i] = B[340 + i];
  __syncthreads();
  int t = blockIdx.x * 256 + tid;
  if (t >= NTV) return;

  float sc[OUTC] = {0.f, 0.f, 0.f, 0.f, 0.f, 0.f, 0.f, 0.f, 0.f, 0.f};
  float sp[OUTC] = {0.f, 0.f, 0.f, 0.f, 0.f, 0.f, 0.f, 0.f, 0.f, 0.f};
  float dc = 0.f, dp = 0.f;
  int e1 = head_tm[t], e2 = head_ti[t];
  while (e1 >= 0 || e2 >= 0) {
    if (e1 >= 0) {
      int4 w0 = tnm[4 * (size_t)e1];
      int4 w1 = tnm[4 * (size_t)e1 + 1];
      int4 w2 = tnm[4 * (size_t)e1 + 2];
      sc[0] += i2f(w0.y); sc[1] += i2f(w0.z); sc[2] += i2f(w0.w);
      sc[3] += i2f(w1.x); sc[4] += i2f(w1.y); sc[5] += i2f(w1.z); sc[6] += i2f(w1.w);
      sc[7] += i2f(w2.x); sc[8] += i2f(w2.y); sc[9] += i2f(w2.z);
      dc += 1.f;
      e1 = w0.x;
    }
    if (e2 >= 0) {
      int4 w0 = tni[4 * (size_t)e2];
      int4 w1 = tni[4 * (size_t)e2 + 1];
      int4 w2 = tni[4 * (size_t)e2 + 2];
      sp[0] += i2f(w0.y); sp[1] += i2f(w0.z); sp[2] += i2f(w0.w);
      sp[3] += i2f(w1.x); sp[4] += i2f(w1.y); sp[5] += i2f(w1.z); sp[6] += i2f(w1.w);
      sp[7] += i2f(w2.x); sp[8] += i2f(w2.y); sp[9] += i2f(w2.z);
      dp += 1.f;
      e2 = w0.x;
    }
  }

  float Gc = dc > 0.f ? 1.f : 0.f, Gp = dp > 0.f ? 1.f : 0.f;
  float ivc = 1.f / fmaxf(dc, 1.f), ivp = 1.f / fmaxf(dp, 1.f);

  const float4* xp4 = (const float4*)(xt + (size_t)t * 8);
  float4 xa = xp4[0], xb = xp4[1];
  float xv[8] = {xa.x, xa.y, xa.z, xa.w, xb.x, xb.y, xb.z, xb.w};

  float lg[OUTC];
  #pragma unroll
  for (int o = 0; o < OUTC; ++o)
    lg[o] = sc[o] * ivc + sp[o] * ivp +
            Gc * sB[80 + o] + Gp * sB[90 + o] + sB[100 + o];
  #pragma unroll
  for (int r = 0; r < 8; ++r) {
    float xr = xv[r];
    #pragma unroll
    for (int o = 0; o < OUTC; ++o) lg[o] += xr * sB[r * 10 + o];
  }

  float m = lg[0];
  #pragma unroll
  for (int o = 1; o < OUTC; ++o) m = fmaxf(m, lg[o]);
  float s = 0.f;
  #pragma unroll
  for (int o = 0; o < OUTC; ++o) { lg[o] = __expf(lg[o] - m); s += lg[o]; }
  float invs = 1.0f / s;
  float* op = &out[(size_t)t * OUTC];
  #pragma unroll
  for (int o = 0; o < 5; ++o) {
    float2 p2; p2.x = lg[2 * o] * invs; p2.y = lg[2 * o + 1] * invs;
    *(float2*)&op[2 * o] = p2;
  }
}

extern "C" void kernel_launch(void* const* d_in, const int* in_sizes, int n_in,
                              void* d_out, int out_size, void* d_ws, size_t ws_size,
                              hipStream_t stream) {
  const float* x_c   = (const float*)d_in[0];
  const float* x_t   = (const float*)d_in[1];
  const float* x_p   = (const float*)d_in[2];
  const float* W_col = (const float*)d_in[3];
  const float* b_col = (const float*)d_in[4];
  const float* Wn    = (const float*)d_in[5];
  const float* Wr    = (const float*)d_in[6];
  const float* b_lin = (const float*)d_in[7];
  const float* W_out = (const float*)d_in[8];
  const float* b_out = (const float*)d_in[9];
  const int* e_m_src = (const int*)d_in[10];
  const int* e_m_dst = (const int*)d_in[11];
  const int* e_i_src = (const int*)d_in[12];
  const int* e_i_dst = (const int*)d_in[13];
  float* out = (float*)d_out;

  // ---- workspace carve-out (~118 MB; ws_size = 256 MiB) ----
  size_t cursor = 0;
  char* base = (char*)d_ws;
  auto alloc = [&](size_t bytes) {
    void* p = base + cursor;
    cursor += (bytes + 255) & ~(size_t)255;
    return p;
  };
  int nheads = NCV + NPV + 2 * NTV;
  int* heads  = (int*)alloc((size_t)nheads * 4);                   // 3.0 MB
  int* head_c  = heads;
  int* head_p  = heads + NCV;
  int* head_tm = heads + NCV + NPV;
  int* head_ti = heads + NCV + NPV + NTV;
  int4* cnm = (int4*)alloc((size_t)EMV * 64);                      // 19.2 MB
  int4* cni = (int4*)alloc((size_t)EIV * 64);                      // 38.4 MB
  int4* tnm = (int4*)alloc((size_t)EMV * 64);                      // 19.2 MB
  int4* tni = (int4*)alloc((size_t)EIV * 64);                      // 38.4 MB
  float* B  = (float*)alloc(450 * 4);

  // ---- K0: fused per-column folding (blocks 0..9) + heads init (blocks 10..127) ----
  fold_heads<<<128, 256, 0, stream>>>(
      W_col, b_col, Wn, Wr, b_lin, W_out, b_out, heads, nheads, B);

  // ---- K1: build lists with fat c/p-nodes (x_t payload + both nexts) ----
  build_graph<<<(EIV + 255) / 256, 256, 0, stream>>>(
      e_m_src, e_m_dst, e_i_src, e_i_dst, x_t,
      head_c, head_p, head_tm, head_ti, cnm, cni);

  // ---- K2: gather over c/p lists + project y + write fat t-nodes ----
  gather_y<<<(NCV + NPV + 255) / 256, 256, 0, stream>>>(
      head_c, head_p, cnm, cni, x_c, x_p, B, tnm, tni);

  // ---- K3: gather over t lists + combine + softmax ----
  gather_t<<<(NTV + 255) / 256, 256, 0, stream>>>(
      tnm, tni, x_t, head_tm, head_ti, B, out);
}

// Round 6
// 270.420 us; speedup vs baseline: 1.2458x; 1.0895x over previous
//
#include <hip/hip_runtime.h>

#define NCV 100000
#define NTV 300000
#define NPV 50000
#define OUTC 10
#define EMV 300000
#define EIV 600000
#define YST 16   // y_c / y_p row stride (floats) -> 64B-aligned rows

__device__ __forceinline__ float i2f(int v) { return __int_as_float(v); }

// ---------------- K0: per-column weight folding (blocks 0..9) + heads init (blocks 10+) ----
// Column o of: T1=Wn10@Wout, T2=Wn12@Wout, T3=0.5*(Wr10+Wr12)@Wout (128 each, LDS)
//             Q1=Wn01@T1 Q2=Wr01@T1 Q3=Wn03@T2 Q4=Wr03@T2 Q5=Wn00@T3 Q6=Wn02@T3 Q7=(Wr00+Wr02)@T3
//             B[:,o]: 45 entries (0..16 B_c | 17..33 B_p | 34..41 B_t | 42 u_c | 43 u_p | 44 k)
__global__ __launch_bounds__(256) void fold_heads(
    const float* __restrict__ Wcol, const float* __restrict__ bcol,
    const float* __restrict__ Wn, const float* __restrict__ Wr,
    const float* __restrict__ b_lin, const float* __restrict__ Wout,
    const float* __restrict__ bout,
    int* __restrict__ heads, int nheads, float* __restrict__ B) {
  int tid = threadIdx.x;
  if (blockIdx.x >= 10) {   // heads init to -1
    int i = (blockIdx.x - 10) * 256 + tid;
    int stride = (gridDim.x - 10) * 256;
    for (; i < nheads; i += stride) heads[i] = -1;
    return;
  }
  __shared__ float sWo[128];
  __shared__ float sT[3][128];
  __shared__ float sQ[7][128];
  const int o = blockIdx.x;
  if (tid < 128) sWo[tid] = Wout[tid * 10 + o];
  __syncthreads();

  const float* Wn00 = Wn;               const float* Wn01 = Wn + 16384;
  const float* Wn02 = Wn + 2 * 16384;   const float* Wn03 = Wn + 3 * 16384;
  const float* Wn10 = Wn + 4 * 16384;   const float* Wn12 = Wn + 6 * 16384;
  const float* Wr00 = Wr;               const float* Wr01 = Wr + 16384;
  const float* Wr02 = Wr + 2 * 16384;   const float* Wr03 = Wr + 3 * 16384;
  const float* Wr10 = Wr + 4 * 16384;   const float* Wr12 = Wr + 6 * 16384;

  // ---- T phase: 3 mats x 128 rows, one dot(128) per task ----
  for (int task = tid; task < 384; task += 256) {
    int mat = task >> 7, n = task & 127;
    float acc = 0.f;
    if (mat == 0) {
      const float4* w = (const float4*)(Wn10 + n * 128);
      for (int m = 0; m < 32; ++m) {
        float4 w4 = w[m];
        acc += w4.x * sWo[4 * m] + w4.y * sWo[4 * m + 1] +
               w4.z * sWo[4 * m + 2] + w4.w * sWo[4 * m + 3];
      }
    } else if (mat == 1) {
      const float4* w = (const float4*)(Wn12 + n * 128);
      for (int m = 0; m < 32; ++m) {
        float4 w4 = w[m];
        acc += w4.x * sWo[4 * m] + w4.y * sWo[4 * m + 1] +
               w4.z * sWo[4 * m + 2] + w4.w * sWo[4 * m + 3];
      }
    } else {
      const float4* wa = (const float4*)(Wr10 + n * 128);
      const float4* wb = (const float4*)(Wr12 + n * 128);
      for (int m = 0; m < 32; ++m) {
        float4 a = wa[m], b = wb[m];
        acc += 0.5f * ((a.x + b.x) * sWo[4 * m] + (a.y + b.y) * sWo[4 * m + 1] +
                       (a.z + b.z) * sWo[4 * m + 2] + (a.w + b.w) * sWo[4 * m + 3]);
      }
    }
    sT[mat][n] = acc;
  }
  __syncthreads();

  // ---- Q phase: 7 mats x 128 rows ----
  for (int task = tid; task < 896; task += 256) {
    int q = task / 128, k = task & 127;
    const float* Tc = sT[q < 2 ? 0 : (q < 4 ? 1 : 2)];
    const float4* w; const float4* w2 = nullptr;
    switch (q) {
      case 0: w = (const float4*)(Wn01 + k * 128); break;
      case 1: w = (const float4*)(Wr01 + k * 128); break;
      case 2: w = (const float4*)(Wn03 + k * 128); break;
      case 3: w = (const float4*)(Wr03 + k * 128); break;
      case 4: w = (const float4*)(Wn00 + k * 128); break;
      case 5: w = (const float4*)(Wn02 + k * 128); break;
      default: w = (const float4*)(Wr00 + k * 128); w2 = (const float4*)(Wr02 + k * 128); break;
    }
    float acc = 0.f;
    for (int n = 0; n < 32; ++n) {
      float4 w4 = w[n];
      if (w2) { float4 b = w2[n]; w4.x += b.x; w4.y += b.y; w4.z += b.z; w4.w += b.w; }
      acc += w4.x * Tc[4 * n] + w4.y * Tc[4 * n + 1] +
             w4.z * Tc[4 * n + 2] + w4.w * Tc[4 * n + 3];
    }
    sQ[q][k] = acc;
  }
  __syncthreads();

  // ---- B phase: 45 rows of column o ----
  if (tid < 45) {
    int r = tid;
    const float* WcC = Wcol, *WcT = Wcol + 128, *WcP = Wcol + 256;
    const float* bC = bcol, *bT = bcol + 128, *bP = bcol + 256;
    const float* b00 = b_lin, *b01 = b_lin + 128, *b02 = b_lin + 256, *b03 = b_lin + 384;
    const float* b10 = b_lin + 512, *b12 = b_lin + 768;
    float s = 0.f;
    if (r < 8) {
      for (int j = 0; j < 16; ++j) s += WcT[r * 16 + j] * sQ[0][r * 16 + j];
    } else if (r < 16) {
      int jr = r - 8;
      for (int j = 0; j < 16; ++j)
        s += WcC[jr * 16 + j] * (sQ[1][jr * 16 + j] + sQ[4][jr * 16 + j]);
    } else if (r == 16) {
      for (int k = 0; k < 128; ++k) s += bT[k] * sQ[0][k];
    } else if (r < 25) {
      int jr = r - 17;
      for (int j = 0; j < 16; ++j) s += WcT[jr * 16 + j] * sQ[2][jr * 16 + j];
    } else if (r < 33) {
      int jr = r - 25;
      for (int j = 0; j < 16; ++j)
        s += WcP[jr * 16 + j] * (sQ[3][jr * 16 + j] + sQ[5][jr * 16 + j]);
    } else if (r == 33) {
      for (int k = 0; k < 128; ++k) s += bT[k] * sQ[2][k];
    } else if (r < 42) {
      int jr = r - 34;
      for (int j = 0; j < 16; ++j) s += WcT[jr * 16 + j] * sQ[6][jr * 16 + j];
    } else if (r == 42) {
      for (int k = 0; k < 128; ++k)
        s += bC[k] * (sQ[1][k] + sQ[4][k]) + b01[k] * sT[0][k];
    } else if (r == 43) {
      for (int k = 0; k < 128; ++k)
        s += bP[k] * (sQ[3][k] + sQ[5][k]) + b03[k] * sT[1][k];
    } else {
      for (int n = 0; n < 128; ++n)
        s += (b10[n] + b12[n]) * sWo[n] + bT[n] * sQ[6][n] + (b00[n] + b02[n]) * sT[2][n];
    }
    float v = s * 0.5f;
    if (r == 44) v += bout[o];
    B[r * 10 + o] = v;
  }
}

// ---------------- K1: build lists ----------------------------------------------------
// Fat c/p-node (64B, coalesced at own index e): {next, x_t[0..2]} {x_t[3..6]} {x_t[7],0,0,0} {0}
// Thin t-node (int2, coalesced at own index e): {next, src}
// x_t row reads are random but issue in the exch latency shadow (+6us measured, r5).
__global__ __launch_bounds__(256) void build_graph(
    const int* __restrict__ ems, const int* __restrict__ emd,
    const int* __restrict__ eis, const int* __restrict__ eid,
    const float* __restrict__ xt,
    int* __restrict__ head_c, int* __restrict__ head_p,
    int* __restrict__ head_tm, int* __restrict__ head_ti,
    int4* __restrict__ cnm, int4* __restrict__ cni,
    int2* __restrict__ tnm, int2* __restrict__ tni) {
  int e = blockIdx.x * 256 + threadIdx.x;
  int4 z = make_int4(0, 0, 0, 0);
  if (e < EMV) {
    int c = ems[e], t = emd[e];
    int cn = atomicExch(&head_c[c], e);
    int tn = atomicExch(&head_tm[t], e);
    const int4* xr = (const int4*)(xt + (size_t)t * 8);
    int4 x0 = xr[0], x1 = xr[1];
    size_t b = 4 * (size_t)e;
    cnm[b]     = make_int4(cn, x0.x, x0.y, x0.z);
    cnm[b + 1] = make_int4(x0.w, x1.x, x1.y, x1.z);
    cnm[b + 2] = make_int4(x1.w, 0, 0, 0);
    cnm[b + 3] = z;
    tnm[e] = make_int2(tn, c);
  }
  if (e < EIV) {
    int p = eis[e], t = eid[e];
    int pn = atomicExch(&head_p[p], e);
    int tn = atomicExch(&head_ti[t], e);
    const int4* xr = (const int4*)(xt + (size_t)t * 8);
    int4 x0 = xr[0], x1 = xr[1];
    size_t b = 4 * (size_t)e;
    cni[b]     = make_int4(pn, x0.x, x0.y, x0.z);
    cni[b + 1] = make_int4(x0.w, x1.x, x1.y, x1.z);
    cni[b + 2] = make_int4(x1.w, 0, 0, 0);
    cni[b + 3] = z;
    tni[e] = make_int2(tn, t >= 0 ? p : p);  // {next, src product}
  }
}

// ---------------- K2: walk fat c/p lists (1 random line/edge), project y --------------
// z = [g*mean_xt, x_own, g] @ B -> 10 floats; y rows written coalesced (full 64B lines).
__global__ __launch_bounds__(256) void gather_y(
    const int* __restrict__ head_c, const int* __restrict__ head_p,
    const int4* __restrict__ cnm, const int4* __restrict__ cni,
    const float* __restrict__ xc, const float* __restrict__ xp,
    const float* __restrict__ B,
    float* __restrict__ y_c, float* __restrict__ y_p) {
  __shared__ float sB[340];   // rows 0..33 of B
  int tid = threadIdx.x;
  for (int i = tid; i < 340; i += 256) sB[i] = B[i];
  __syncthreads();
  int i = blockIdx.x * 256 + tid;
  if (i >= NCV + NPV) return;
  bool isC = i < NCV;
  int idx = isC ? i : i - NCV;
  const int4* cn = isC ? cnm : cni;
  int e = isC ? head_c[idx] : head_p[idx];

  float acc[8] = {0.f, 0.f, 0.f, 0.f, 0.f, 0.f, 0.f, 0.f};
  float cnt = 0.f;
  while (e >= 0) {
    size_t b = 4 * (size_t)e;
    int4 w0 = cn[b];
    int4 w1 = cn[b + 1];
    int4 w2 = cn[b + 2];
    acc[0] += i2f(w0.y); acc[1] += i2f(w0.z); acc[2] += i2f(w0.w);
    acc[3] += i2f(w1.x); acc[4] += i2f(w1.y); acc[5] += i2f(w1.z); acc[6] += i2f(w1.w);
    acc[7] += i2f(w2.x);
    cnt += 1.f;
    e = w0.x;
  }

  const float* xo = (isC ? xc : xp) + (size_t)idx * 8;
  const float* Bs = sB + (isC ? 0 : 170);
  float gg = cnt > 0.f ? 1.f : 0.f;
  float inv = gg / fmaxf(cnt, 1.f);
  float lg[OUTC];
  #pragma unroll
  for (int o = 0; o < OUTC; ++o) lg[o] = gg * Bs[16 * 10 + o];
  #pragma unroll
  for (int r = 0; r < 8; ++r) {
    float zb = acc[r] * inv;
    float zo = xo[r];
    #pragma unroll
    for (int o = 0; o < OUTC; ++o)
      lg[o] += zb * Bs[r * 10 + o] + zo * Bs[(8 + r) * 10 + o];
  }
  float4* yv = (float4*)((isC ? y_c : y_p) + (size_t)idx * YST);
  yv[0] = make_float4(lg[0], lg[1], lg[2], lg[3]);
  yv[1] = make_float4(lg[4], lg[5], lg[6], lg[7]);
  yv[2] = make_float4(lg[8], lg[9], 0.f, 0.f);
  yv[3] = make_float4(0.f, 0.f, 0.f, 0.f);
}

// ---------------- K3: dual interleaved thin-node walks + y reads (L2-reused) + softmax -
__global__ __launch_bounds__(256) void gather_t(
    const float* __restrict__ y_c, const float* __restrict__ y_p,
    const float* __restrict__ xt,
    const int* __restrict__ head_tm, const int* __restrict__ head_ti,
    const int2* __restrict__ tnm, const int2* __restrict__ tni,
    const float* __restrict__ B, float* __restrict__ out) {
  __shared__ float sB[110];   // rows 34..44 of B
  int tid = threadIdx.x;
  for (int i = tid; i < 110; i += 256) sB[i] = B[340 + i];
  __syncthreads();
  int t = blockIdx.x * 256 + tid;
  if (t >= NTV) return;

  float sc[OUTC] = {0.f, 0.f, 0.f, 0.f, 0.f, 0.f, 0.f, 0.f, 0.f, 0.f};
  float sp[OUTC] = {0.f, 0.f, 0.f, 0.f, 0.f, 0.f, 0.f, 0.f, 0.f, 0.f};
  float dc = 0.f, dp = 0.f;
  int e1 = head_tm[t], e2 = head_ti[t];
  while (e1 >= 0 || e2 >= 0) {
    if (e1 >= 0) {
      int2 v = tnm[e1];
      const float* yr = y_c + (size_t)v.y * YST;
      float4 u = *(const float4*)yr;
      float4 w = *(const float4*)(yr + 4);
      float2 z = *(const float2*)(yr + 8);
      sc[0] += u.x; sc[1] += u.y; sc[2] += u.z; sc[3] += u.w;
      sc[4] += w.x; sc[5] += w.y; sc[6] += w.z; sc[7] += w.w;
      sc[8] += z.x; sc[9] += z.y;
      dc += 1.f;
      e1 = v.x;
    }
    if (e2 >= 0) {
      int2 v = tni[e2];
      const float* yr = y_p + (size_t)v.y * YST;
      float4 u = *(const float4*)yr;
      float4 w = *(const float4*)(yr + 4);
      float2 z = *(const float2*)(yr + 8);
      sp[0] += u.x; sp[1] += u.y; sp[2] += u.z; sp[3] += u.w;
      sp[4] += w.x; sp[5] += w.y; sp[6] += w.z; sp[7] += w.w;
      sp[8] += z.x; sp[9] += z.y;
      dp += 1.f;
      e2 = v.x;
    }
  }

  float Gc = dc > 0.f ? 1.f : 0.f, Gp = dp > 0.f ? 1.f : 0.f;
  float ivc = 1.f / fmaxf(dc, 1.f), ivp = 1.f / fmaxf(dp, 1.f);

  const float4* xp4 = (const float4*)(xt + (size_t)t * 8);
  float4 xa = xp4[0], xb = xp4[1];
  float xv[8] = {xa.x, xa.y, xa.z, xa.w, xb.x, xb.y, xb.z, xb.w};

  float lg[OUTC];
  #pragma unroll
  for (int o = 0; o < OUTC; ++o)
    lg[o] = sc[o] * ivc + sp[o] * ivp +
            Gc * sB[80 + o] + Gp * sB[90 + o] + sB[100 + o];
  #pragma unroll
  for (int r = 0; r < 8; ++r) {
    float xr = xv[r];
    #pragma unroll
    for (int o = 0; o < OUTC; ++o) lg[o] += xr * sB[r * 10 + o];
  }

  float m = lg[0];
  #pragma unroll
  for (int o = 1; o < OUTC; ++o) m = fmaxf(m, lg[o]);
  float s = 0.f;
  #pragma unroll
  for (int o = 0; o < OUTC; ++o) { lg[o] = __expf(lg[o] - m); s += lg[o]; }
  float invs = 1.0f / s;
  float* op = &out[(size_t)t * OUTC];
  #pragma unroll
  for (int o = 0; o < 5; ++o) {
    float2 p2; p2.x = lg[2 * o] * invs; p2.y = lg[2 * o + 1] * invs;
    *(float2*)&op[2 * o] = p2;
  }
}

extern "C" void kernel_launch(void* const* d_in, const int* in_sizes, int n_in,
                              void* d_out, int out_size, void* d_ws, size_t ws_size,
                              hipStream_t stream) {
  const float* x_c   = (const float*)d_in[0];
  const float* x_t   = (const float*)d_in[1];
  const float* x_p   = (const float*)d_in[2];
  const float* W_col = (const float*)d_in[3];
  const float* b_col = (const float*)d_in[4];
  const float* Wn    = (const float*)d_in[5];
  const float* Wr    = (const float*)d_in[6];
  const float* b_lin = (const float*)d_in[7];
  const float* W_out = (const float*)d_in[8];
  const float* b_out = (const float*)d_in[9];
  const int* e_m_src = (const int*)d_in[10];
  const int* e_m_dst = (const int*)d_in[11];
  const int* e_i_src = (const int*)d_in[12];
  const int* e_i_dst = (const int*)d_in[13];
  float* out = (float*)d_out;

  // ---- workspace carve-out (~78 MB; ws_size = 256 MiB) ----
  size_t cursor = 0;
  char* base = (char*)d_ws;
  auto alloc = [&](size_t bytes) {
    void* p = base + cursor;
    cursor += (bytes + 255) & ~(size_t)255;
    return p;
  };
  int nheads = NCV + NPV + 2 * NTV;
  int* heads  = (int*)alloc((size_t)nheads * 4);                   // 3.0 MB
  int* head_c  = heads;
  int* head_p  = heads + NCV;
  int* head_tm = heads + NCV + NPV;
  int* head_ti = heads + NCV + NPV + NTV;
  int4* cnm = (int4*)alloc((size_t)EMV * 64);                      // 19.2 MB
  int4* cni = (int4*)alloc((size_t)EIV * 64);                      // 38.4 MB
  int2* tnm = (int2*)alloc((size_t)EMV * 8);                       // 2.4 MB
  int2* tni = (int2*)alloc((size_t)EIV * 8);                       // 4.8 MB
  float* y_c = (float*)alloc((size_t)NCV * YST * 4);               // 6.4 MB
  float* y_p = (float*)alloc((size_t)NPV * YST * 4);               // 3.2 MB
  float* B   = (float*)alloc(450 * 4);

  // ---- K0: fused per-column folding (blocks 0..9) + heads init (blocks 10..127) ----
  fold_heads<<<128, 256, 0, stream>>>(
      W_col, b_col, Wn, Wr, b_lin, W_out, b_out, heads, nheads, B);

  // ---- K1: build lists (fat c/p-nodes with x_t payload; thin int2 t-nodes) ----
  build_graph<<<(EIV + 255) / 256, 256, 0, stream>>>(
      e_m_src, e_m_dst, e_i_src, e_i_dst, x_t,
      head_c, head_p, head_tm, head_ti, cnm, cni, tnm, tni);

  // ---- K2: gather over fat c/p lists + project y (coalesced y writes) ----
  gather_y<<<(NCV + NPV + 255) / 256, 256, 0, stream>>>(
      head_c, head_p, cnm, cni, x_c, x_p, B, y_c, y_p);

  // ---- K3: gather over thin t lists + y reads + combine + softmax ----
  gather_t<<<(NTV + 255) / 256, 256, 0, stream>>>(
      y_c, y_p, x_t, head_tm, head_ti, tnm, tni, B, out);
}